// Round 1
// baseline (727.154 us; speedup 1.0000x reference)
//
#include <hip/hip_runtime.h>
#include <hip/hip_bf16.h>
#include <stdint.h>

// ---------------------------------------------------------------------------
// GCN 2-layer: out = A_norm @ relu(A_norm @ (x@W1) + b1) @ W2 + b2
// where A_norm has self-loops and symmetric rsqrt-degree normalization.
// Restructured: g = (x@W)*dis[row];  out[i] = dis[i]*(sum_{e->i} g[src] + g[i]) + b
// ---------------------------------------------------------------------------

// Detect whether edge_index buffer is int64 (odd 32-bit words all zero) or int32.
__global__ void detect_i64_kernel(const int* __restrict__ idx, int* __restrict__ flag) {
    int t = threadIdx.x;
    int v = idx[2 * t + 1];
    unsigned long long b = __ballot(v == 0);
    if (t == 0) *flag = (b == 0xFFFFFFFFFFFFFFFFULL) ? 1 : 0;
}

__device__ __forceinline__ int load_idx(const int* __restrict__ idx, long long pos, int is64) {
    return is64 ? idx[2 * pos] : idx[pos];   // little-endian low word for int64
}

__global__ void count_edges_kernel(const int* __restrict__ idx, const int* __restrict__ flag,
                                   int* __restrict__ counts, int E, int N) {
    int e = blockIdx.x * blockDim.x + threadIdx.x;
    if (e >= E) return;
    int is64 = *flag;
    int d = load_idx(idx, (long long)E + e, is64);
    if ((unsigned)d < (unsigned)N) atomicAdd(&counts[d], 1);
}

// Single-block exclusive scan over counts -> offsets (+ cursor copy, + dis = rsqrt(deg+1)).
__global__ void scan_kernel(const int* __restrict__ counts, int* __restrict__ offsets,
                            int* __restrict__ cursor, float* __restrict__ dis, int n) {
    __shared__ int buf[1024];
    __shared__ int carry_s;
    if (threadIdx.x == 0) carry_s = 0;
    __syncthreads();
    for (int base = 0; base < n; base += 1024) {
        int i = base + (int)threadIdx.x;
        int v = (i < n) ? counts[i] : 0;
        buf[threadIdx.x] = v;
        __syncthreads();
        for (int off = 1; off < 1024; off <<= 1) {
            int t = (threadIdx.x >= (unsigned)off) ? buf[threadIdx.x - off] : 0;
            __syncthreads();
            buf[threadIdx.x] += t;
            __syncthreads();
        }
        int incl = buf[threadIdx.x];
        int carry = carry_s;
        if (i < n) {
            int excl = carry + incl - v;
            offsets[i] = excl;
            cursor[i] = excl;
            dis[i] = rsqrtf((float)(v + 1));   // +1 self-loop; deg >= 1 always
        }
        __syncthreads();
        if (threadIdx.x == 1023) carry_s = carry + buf[1023];
        __syncthreads();
    }
    if (threadIdx.x == 0) offsets[n] = carry_s;
}

__global__ void fill_csr_kernel(const int* __restrict__ idx, const int* __restrict__ flag,
                                int* __restrict__ cursor, int* __restrict__ csr_src,
                                int E, int N) {
    int e = blockIdx.x * blockDim.x + threadIdx.x;
    if (e >= E) return;
    int is64 = *flag;
    int s = load_idx(idx, e, is64);
    int d = load_idx(idx, (long long)E + e, is64);
    if ((unsigned)d < (unsigned)N) {
        int pos = atomicAdd(&cursor[d], 1);
        csr_src[pos] = ((unsigned)s < (unsigned)N) ? s : 0;
    }
}

// Tiled f32 GEMM: C[M x Nc] = (A[M x K] @ B[K x Nc]) * dis[row]
// BM=128, BN=64, BK=16, TM=8, TN=4, 256 threads.
#define BM 128
#define BN 64
#define BK 16
#define TM 8
#define TN 4

__global__ __launch_bounds__(256) void gemm_scale_kernel(
        const float* __restrict__ A, const float* __restrict__ B,
        const float* __restrict__ dis, float* __restrict__ C,
        int M, int Nc, int K) {
    __shared__ float As[BK][BM + 4];
    __shared__ float Bs[BK][BN];
    const int tid = threadIdx.x;
    const int brow = blockIdx.y * BM;
    const int bcol = blockIdx.x * BN;
    const int tcol = (tid % (BN / TN)) * TN;   // 16 thread-cols
    const int trow = (tid / (BN / TN)) * TM;   // 16 thread-rows

    float acc[TM][TN];
    #pragma unroll
    for (int i = 0; i < TM; ++i)
        #pragma unroll
        for (int j = 0; j < TN; ++j) acc[i][j] = 0.f;

    for (int k0 = 0; k0 < K; k0 += BK) {
        // A tile: BM x BK (2048 elems / 256 thr = 8 each); contiguous in k.
        #pragma unroll
        for (int it = 0; it < (BM * BK) / 256; ++it) {
            int idx = tid + it * 256;
            int m = idx / BK, kk = idx % BK;
            int gr = brow + m;
            As[kk][m] = (gr < M) ? A[(size_t)gr * K + k0 + kk] : 0.f;
        }
        // B tile: BK x BN (1024 elems / 256 thr = 4 each); contiguous in n.
        #pragma unroll
        for (int it = 0; it < (BK * BN) / 256; ++it) {
            int idx = tid + it * 256;
            int kk = idx / BN, n = idx % BN;
            Bs[kk][n] = B[(size_t)(k0 + kk) * Nc + bcol + n];
        }
        __syncthreads();
        #pragma unroll
        for (int kk = 0; kk < BK; ++kk) {
            float a[TM], b[TN];
            #pragma unroll
            for (int i = 0; i < TM; ++i) a[i] = As[kk][trow + i];
            #pragma unroll
            for (int j = 0; j < TN; ++j) b[j] = Bs[kk][tcol + j];
            #pragma unroll
            for (int i = 0; i < TM; ++i)
                #pragma unroll
                for (int j = 0; j < TN; ++j)
                    acc[i][j] = fmaf(a[i], b[j], acc[i][j]);
        }
        __syncthreads();
    }
    #pragma unroll
    for (int i = 0; i < TM; ++i) {
        int gr = brow + trow + i;
        if (gr >= M) continue;
        float s = dis[gr];
        #pragma unroll
        for (int j = 0; j < TN; ++j)
            C[(size_t)gr * Nc + bcol + tcol + j] = acc[i][j] * s;
    }
}

// Per-node CSR gather-sum: out[i,c] = act(dis[i]*(sum_{e->i} g[src_e,c] + g[i,c]) + bias[c])
// One block per node, C threads (C = 256 or 64).
__global__ void agg_kernel(const float* __restrict__ g, const int* __restrict__ offsets,
                           const int* __restrict__ csr_src, const float* __restrict__ dis,
                           const float* __restrict__ bias, float* __restrict__ out,
                           int C, int do_relu) {
    int node = blockIdx.x;
    int c = threadIdx.x;
    float sum = g[(size_t)node * C + c];        // self-loop term (g already *dis[src])
    int s0 = offsets[node], s1 = offsets[node + 1];
    for (int e = s0; e < s1; ++e) {
        int s = csr_src[e];
        sum += g[(size_t)s * C + c];
    }
    float v = fmaf(dis[node], sum, bias[c]);
    out[(size_t)node * C + c] = do_relu ? fmaxf(v, 0.f) : v;
}

extern "C" void kernel_launch(void* const* d_in, const int* in_sizes, int n_in,
                              void* d_out, int out_size, void* d_ws, size_t ws_size,
                              hipStream_t stream) {
    const float* x  = (const float*)d_in[0];
    const float* W1 = (const float*)d_in[1];
    const float* b1 = (const float*)d_in[2];
    const float* W2 = (const float*)d_in[3];
    const float* b2 = (const float*)d_in[4];
    const int* eidx = (const int*)d_in[5];

    const int HID = in_sizes[2];            // 256
    const int OUT = in_sizes[4];            // 64
    const int IN  = in_sizes[1] / HID;      // 512
    const int N   = in_sizes[0] / IN;       // 50000
    const int E   = in_sizes[5] / 2;        // 800000

    char* ws = (char*)d_ws;
    size_t off = 0;
    auto alloc = [&](size_t bytes) {
        off = (off + 255) & ~(size_t)255;
        char* p = ws + off;
        off += bytes;
        return p;
    };
    float* dis   = (float*)alloc((size_t)N * 4);
    int* counts  = (int*)alloc((size_t)N * 4);
    int* offsets = (int*)alloc((size_t)(N + 1) * 4);
    int* cursor  = (int*)alloc((size_t)N * 4);
    int* flag    = (int*)alloc(256);
    int* csr_src = (int*)alloc((size_t)E * 4);
    float* h1    = (float*)alloc((size_t)N * HID * 4);   // g1 = (x@W1)*dis
    float* a1    = (float*)alloc((size_t)N * HID * 4);   // relu(agg1 + b1)
    float* h2    = (float*)alloc((size_t)N * OUT * 4);   // g2 = (a1@W2)*dis

    hipMemsetAsync(counts, 0, (size_t)N * 4, stream);
    detect_i64_kernel<<<1, 64, 0, stream>>>(eidx, flag);
    count_edges_kernel<<<(E + 255) / 256, 256, 0, stream>>>(eidx, flag, counts, E, N);
    scan_kernel<<<1, 1024, 0, stream>>>(counts, offsets, cursor, dis, N);
    fill_csr_kernel<<<(E + 255) / 256, 256, 0, stream>>>(eidx, flag, cursor, csr_src, E, N);

    // Layer 1: g1 = (x @ W1) * dis
    dim3 grid1(HID / BN, (N + BM - 1) / BM);
    gemm_scale_kernel<<<grid1, 256, 0, stream>>>(x, W1, dis, h1, N, HID, IN);
    agg_kernel<<<N, HID, 0, stream>>>(h1, offsets, csr_src, dis, b1, a1, HID, 1);

    // Layer 2: g2 = (a1 @ W2) * dis
    dim3 grid2(OUT / BN, (N + BM - 1) / BM);
    gemm_scale_kernel<<<grid2, 256, 0, stream>>>(a1, W2, dis, h2, N, OUT, HID);
    agg_kernel<<<N, OUT, 0, stream>>>(h2, offsets, csr_src, dis, b2, (float*)d_out, OUT, 0);
}

// Round 2
// 586.424 us; speedup vs baseline: 1.2400x; 1.2400x over previous
//
#include <hip/hip_runtime.h>
#include <hip/hip_bf16.h>
#include <stdint.h>

// ---------------------------------------------------------------------------
// GCN 2-layer: out = A_norm @ relu(A_norm @ (x@W1) + b1) @ W2 + b2
// Restructured: g = (x@W)*dis[row];  out[i] = dis[i]*(sum_{e->i} g[src] + g[i]) + b
// ---------------------------------------------------------------------------

__global__ void detect_i64_kernel(const int* __restrict__ idx, int* __restrict__ flag) {
    int t = threadIdx.x;
    int v = idx[2 * t + 1];
    unsigned long long b = __ballot(v == 0);
    if (t == 0) *flag = (b == 0xFFFFFFFFFFFFFFFFULL) ? 1 : 0;
}

__device__ __forceinline__ int load_idx(const int* __restrict__ idx, long long pos, int is64) {
    return is64 ? idx[2 * pos] : idx[pos];
}

__global__ void count_edges_kernel(const int* __restrict__ idx, const int* __restrict__ flag,
                                   int* __restrict__ counts, int E, int N) {
    int e = blockIdx.x * blockDim.x + threadIdx.x;
    if (e >= E) return;
    int is64 = *flag;
    int d = load_idx(idx, (long long)E + e, is64);
    if ((unsigned)d < (unsigned)N) atomicAdd(&counts[d], 1);
}

__global__ void scan_kernel(const int* __restrict__ counts, int* __restrict__ offsets,
                            int* __restrict__ cursor, float* __restrict__ dis, int n) {
    __shared__ int buf[1024];
    __shared__ int carry_s;
    if (threadIdx.x == 0) carry_s = 0;
    __syncthreads();
    for (int base = 0; base < n; base += 1024) {
        int i = base + (int)threadIdx.x;
        int v = (i < n) ? counts[i] : 0;
        buf[threadIdx.x] = v;
        __syncthreads();
        for (int off = 1; off < 1024; off <<= 1) {
            int t = (threadIdx.x >= (unsigned)off) ? buf[threadIdx.x - off] : 0;
            __syncthreads();
            buf[threadIdx.x] += t;
            __syncthreads();
        }
        int incl = buf[threadIdx.x];
        int carry = carry_s;
        if (i < n) {
            int excl = carry + incl - v;
            offsets[i] = excl;
            cursor[i] = excl;
            dis[i] = rsqrtf((float)(v + 1));
        }
        __syncthreads();
        if (threadIdx.x == 1023) carry_s = carry + buf[1023];
        __syncthreads();
    }
    if (threadIdx.x == 0) offsets[n] = carry_s;
}

__global__ void fill_csr_kernel(const int* __restrict__ idx, const int* __restrict__ flag,
                                int* __restrict__ cursor, int* __restrict__ csr_src,
                                int E, int N) {
    int e = blockIdx.x * blockDim.x + threadIdx.x;
    if (e >= E) return;
    int is64 = *flag;
    int s = load_idx(idx, e, is64);
    int d = load_idx(idx, (long long)E + e, is64);
    if ((unsigned)d < (unsigned)N) {
        int pos = atomicAdd(&cursor[d], 1);
        csr_src[pos] = ((unsigned)s < (unsigned)N) ? s : 0;
    }
}

// ---------------------------------------------------------------------------
// GEMM A[M,K] @ B[K,Nc] * dis[row] -> C. 128x128 tile, 8x8 micro, 256 thr.
// ---------------------------------------------------------------------------
__global__ __launch_bounds__(256) void gemm128_kernel(
        const float* __restrict__ A, const float* __restrict__ B,
        const float* __restrict__ dis, float* __restrict__ C,
        int M, int Nc, int K) {
    __shared__ float As[16][132];
    __shared__ float Bs[16][128];
    const int tid = threadIdx.x;
    const int brow = blockIdx.y * 128;
    const int bcol = blockIdx.x * 128;
    const int trow = (tid / 16) * 8;
    const int tcol = (tid % 16) * 8;

    const int ar0 = tid / 4;          // A-stage row (0..63), +64 second half
    const int aq  = tid % 4;          // A-stage k-quad
    const int bk0 = tid / 32;         // B-stage k (0..7), +8 second half
    const int bq  = tid % 32;         // B-stage col-quad

    float acc[8][8];
    #pragma unroll
    for (int i = 0; i < 8; ++i)
        #pragma unroll
        for (int j = 0; j < 8; ++j) acc[i][j] = 0.f;

    for (int k0 = 0; k0 < K; k0 += 16) {
        #pragma unroll
        for (int half = 0; half < 2; ++half) {
            int row = ar0 + half * 64;
            int gr = brow + row;
            float4 v = make_float4(0.f, 0.f, 0.f, 0.f);
            if (gr < M) v = *(const float4*)&A[(size_t)gr * K + k0 + aq * 4];
            As[aq * 4 + 0][row] = v.x;
            As[aq * 4 + 1][row] = v.y;
            As[aq * 4 + 2][row] = v.z;
            As[aq * 4 + 3][row] = v.w;
        }
        #pragma unroll
        for (int half = 0; half < 2; ++half) {
            int kk = bk0 + half * 8;
            *(float4*)&Bs[kk][bq * 4] =
                *(const float4*)&B[(size_t)(k0 + kk) * Nc + bcol + bq * 4];
        }
        __syncthreads();
        #pragma unroll
        for (int kk = 0; kk < 16; ++kk) {
            float a[8], b[8];
            *(float4*)&a[0] = *(const float4*)&As[kk][trow];
            *(float4*)&a[4] = *(const float4*)&As[kk][trow + 4];
            *(float4*)&b[0] = *(const float4*)&Bs[kk][tcol];
            *(float4*)&b[4] = *(const float4*)&Bs[kk][tcol + 4];
            #pragma unroll
            for (int i = 0; i < 8; ++i)
                #pragma unroll
                for (int j = 0; j < 8; ++j)
                    acc[i][j] = fmaf(a[i], b[j], acc[i][j]);
        }
        __syncthreads();
    }
    #pragma unroll
    for (int i = 0; i < 8; ++i) {
        int gr = brow + trow + i;
        if (gr >= M) continue;
        float s = dis[gr];
        float4 o0 = make_float4(acc[i][0] * s, acc[i][1] * s, acc[i][2] * s, acc[i][3] * s);
        float4 o1 = make_float4(acc[i][4] * s, acc[i][5] * s, acc[i][6] * s, acc[i][7] * s);
        *(float4*)&C[(size_t)gr * Nc + bcol + tcol]     = o0;
        *(float4*)&C[(size_t)gr * Nc + bcol + tcol + 4] = o1;
    }
}

// 64x64 tile, 4x4 micro, 256 threads — for the skinny second GEMM.
__global__ __launch_bounds__(256) void gemm64_kernel(
        const float* __restrict__ A, const float* __restrict__ B,
        const float* __restrict__ dis, float* __restrict__ C,
        int M, int Nc, int K) {
    __shared__ float As[16][68];
    __shared__ float Bs[16][64];
    const int tid = threadIdx.x;
    const int brow = blockIdx.y * 64;
    const int bcol = blockIdx.x * 64;
    const int trow = (tid / 16) * 4;
    const int tcol = (tid % 16) * 4;

    const int ar = tid / 4;           // 0..63
    const int aq = tid % 4;
    const int bk = tid / 16;          // 0..15
    const int bq2 = tid % 16;

    float acc[4][4];
    #pragma unroll
    for (int i = 0; i < 4; ++i)
        #pragma unroll
        for (int j = 0; j < 4; ++j) acc[i][j] = 0.f;

    for (int k0 = 0; k0 < K; k0 += 16) {
        int gr = brow + ar;
        float4 v = make_float4(0.f, 0.f, 0.f, 0.f);
        if (gr < M) v = *(const float4*)&A[(size_t)gr * K + k0 + aq * 4];
        As[aq * 4 + 0][ar] = v.x;
        As[aq * 4 + 1][ar] = v.y;
        As[aq * 4 + 2][ar] = v.z;
        As[aq * 4 + 3][ar] = v.w;
        *(float4*)&Bs[bk][bq2 * 4] =
            *(const float4*)&B[(size_t)(k0 + bk) * Nc + bcol + bq2 * 4];
        __syncthreads();
        #pragma unroll
        for (int kk = 0; kk < 16; ++kk) {
            float a[4], b[4];
            *(float4*)&a[0] = *(const float4*)&As[kk][trow];
            *(float4*)&b[0] = *(const float4*)&Bs[kk][tcol];
            #pragma unroll
            for (int i = 0; i < 4; ++i)
                #pragma unroll
                for (int j = 0; j < 4; ++j)
                    acc[i][j] = fmaf(a[i], b[j], acc[i][j]);
        }
        __syncthreads();
    }
    #pragma unroll
    for (int i = 0; i < 4; ++i) {
        int gr = brow + trow + i;
        if (gr >= M) continue;
        float s = dis[gr];
        float4 o = make_float4(acc[i][0] * s, acc[i][1] * s, acc[i][2] * s, acc[i][3] * s);
        *(float4*)&C[(size_t)gr * Nc + bcol + tcol] = o;
    }
}

// ---------------------------------------------------------------------------
// Aggregation, C=256: one node/block, 4 waves = 4 edge slots, float4 lanes.
// out[i,c] = relu?(dis[i]*(sum_e g[src_e,c] + g[i,c]) + bias[c])
// ---------------------------------------------------------------------------
__global__ __launch_bounds__(256) void agg256_kernel(
        const float* __restrict__ g, const int* __restrict__ offsets,
        const int* __restrict__ csr_src, const float* __restrict__ dis,
        const float* __restrict__ bias, float* __restrict__ out, int do_relu) {
    const int node = blockIdx.x;
    const int w = threadIdx.x >> 6;
    const int lane = threadIdx.x & 63;
    const float4* gv = (const float4*)g;          // row = 64 float4
    float4 acc = make_float4(0.f, 0.f, 0.f, 0.f);
    const int s0 = offsets[node], s1 = offsets[node + 1];
    for (int e = s0 + w; e < s1; e += 4) {
        int s = csr_src[e];
        float4 v = gv[(size_t)s * 64 + lane];
        acc.x += v.x; acc.y += v.y; acc.z += v.z; acc.w += v.w;
    }
    if (w == 0) {
        float4 v = gv[(size_t)node * 64 + lane];
        acc.x += v.x; acc.y += v.y; acc.z += v.z; acc.w += v.w;
    }
    __shared__ float4 red[4][64];
    red[w][lane] = acc;
    __syncthreads();
    if (w == 0) {
        float4 a = red[0][lane], b = red[1][lane], c = red[2][lane], d = red[3][lane];
        float s = dis[node];
        float4 bb = ((const float4*)bias)[lane];
        float4 o;
        o.x = fmaf(s, a.x + b.x + c.x + d.x, bb.x);
        o.y = fmaf(s, a.y + b.y + c.y + d.y, bb.y);
        o.z = fmaf(s, a.z + b.z + c.z + d.z, bb.z);
        o.w = fmaf(s, a.w + b.w + c.w + d.w, bb.w);
        if (do_relu) {
            o.x = fmaxf(o.x, 0.f); o.y = fmaxf(o.y, 0.f);
            o.z = fmaxf(o.z, 0.f); o.w = fmaxf(o.w, 0.f);
        }
        ((float4*)out)[(size_t)node * 64 + lane] = o;
    }
}

// Aggregation, C=64: 4 waves/block, wave = one node; lane = 16 cols x 4 slots.
__global__ __launch_bounds__(256) void agg64_kernel(
        const float* __restrict__ g, const int* __restrict__ offsets,
        const int* __restrict__ csr_src, const float* __restrict__ dis,
        const float* __restrict__ bias, float* __restrict__ out,
        int n_nodes, int do_relu) {
    const int node = blockIdx.x * 4 + (threadIdx.x >> 6);
    if (node >= n_nodes) return;
    const int lane = threadIdx.x & 63;
    const int eslot = lane >> 4;          // 0..3
    const int c = lane & 15;              // float4 column
    const float4* gv = (const float4*)g;  // row = 16 float4
    float4 acc = make_float4(0.f, 0.f, 0.f, 0.f);
    const int s0 = offsets[node], s1 = offsets[node + 1];
    for (int e = s0 + eslot; e < s1; e += 4) {
        int s = csr_src[e];
        float4 v = gv[(size_t)s * 16 + c];
        acc.x += v.x; acc.y += v.y; acc.z += v.z; acc.w += v.w;
    }
    if (eslot == 0) {
        float4 v = gv[(size_t)node * 16 + c];
        acc.x += v.x; acc.y += v.y; acc.z += v.z; acc.w += v.w;
    }
    #pragma unroll
    for (int m = 16; m <= 32; m <<= 1) {
        acc.x += __shfl_xor(acc.x, m);
        acc.y += __shfl_xor(acc.y, m);
        acc.z += __shfl_xor(acc.z, m);
        acc.w += __shfl_xor(acc.w, m);
    }
    if (eslot == 0) {
        float s = dis[node];
        float4 bb = ((const float4*)bias)[c];
        float4 o;
        o.x = fmaf(s, acc.x, bb.x);
        o.y = fmaf(s, acc.y, bb.y);
        o.z = fmaf(s, acc.z, bb.z);
        o.w = fmaf(s, acc.w, bb.w);
        if (do_relu) {
            o.x = fmaxf(o.x, 0.f); o.y = fmaxf(o.y, 0.f);
            o.z = fmaxf(o.z, 0.f); o.w = fmaxf(o.w, 0.f);
        }
        ((float4*)out)[(size_t)node * 16 + c] = o;
    }
}

extern "C" void kernel_launch(void* const* d_in, const int* in_sizes, int n_in,
                              void* d_out, int out_size, void* d_ws, size_t ws_size,
                              hipStream_t stream) {
    const float* x  = (const float*)d_in[0];
    const float* W1 = (const float*)d_in[1];
    const float* b1 = (const float*)d_in[2];
    const float* W2 = (const float*)d_in[3];
    const float* b2 = (const float*)d_in[4];
    const int* eidx = (const int*)d_in[5];

    const int HID = in_sizes[2];            // 256
    const int OUT = in_sizes[4];            // 64
    const int IN  = in_sizes[1] / HID;      // 512
    const int N   = in_sizes[0] / IN;       // 50000
    const int E   = in_sizes[5] / 2;        // 800000

    char* ws = (char*)d_ws;
    size_t off = 0;
    auto alloc = [&](size_t bytes) {
        off = (off + 255) & ~(size_t)255;
        char* p = ws + off;
        off += bytes;
        return p;
    };
    float* dis   = (float*)alloc((size_t)N * 4);
    int* counts  = (int*)alloc((size_t)N * 4);
    int* offsets = (int*)alloc((size_t)(N + 1) * 4);
    int* cursor  = (int*)alloc((size_t)N * 4);
    int* flag    = (int*)alloc(256);
    int* csr_src = (int*)alloc((size_t)E * 4);
    float* h1    = (float*)alloc((size_t)N * HID * 4);
    float* a1    = (float*)alloc((size_t)N * HID * 4);
    float* h2    = (float*)alloc((size_t)N * OUT * 4);

    hipMemsetAsync(counts, 0, (size_t)N * 4, stream);
    detect_i64_kernel<<<1, 64, 0, stream>>>(eidx, flag);
    count_edges_kernel<<<(E + 255) / 256, 256, 0, stream>>>(eidx, flag, counts, E, N);
    scan_kernel<<<1, 1024, 0, stream>>>(counts, offsets, cursor, dis, N);
    fill_csr_kernel<<<(E + 255) / 256, 256, 0, stream>>>(eidx, flag, cursor, csr_src, E, N);

    // Layer 1: h1 = (x @ W1) * dis ; a1 = relu(agg(h1) + b1)
    dim3 grid1(HID / 128, (N + 127) / 128);
    gemm128_kernel<<<grid1, 256, 0, stream>>>(x, W1, dis, h1, N, HID, IN);
    agg256_kernel<<<N, 256, 0, stream>>>(h1, offsets, csr_src, dis, b1, a1, 1);

    // Layer 2: h2 = (a1 @ W2) * dis ; out = agg(h2) + b2
    dim3 grid2(OUT / 64, (N + 63) / 64);
    gemm64_kernel<<<grid2, 256, 0, stream>>>(a1, W2, dis, h2, N, OUT, HID);
    agg64_kernel<<<(N + 3) / 4, 256, 0, stream>>>(h2, offsets, csr_src, dis, b2,
                                                  (float*)d_out, N, 0);
}

// Round 3
// 321.354 us; speedup vs baseline: 2.2628x; 1.8249x over previous
//
#include <hip/hip_runtime.h>
#include <hip/hip_bf16.h>
#include <hip/hip_fp16.h>
#include <stdint.h>

typedef _Float16 half8_t __attribute__((ext_vector_type(8)));
typedef float f32x4_t __attribute__((ext_vector_type(4)));

// ---------------------------------------------------------------------------
// GCN 2-layer, fp16-MFMA path:
//   g = (x@W)*dis[row] (fp16 storage);  out[i] = dis[i]*(sum_e g[src]+g[i]) + b
// ---------------------------------------------------------------------------

__global__ void detect_i64_kernel(const int* __restrict__ idx, int* __restrict__ flag) {
    int t = threadIdx.x;
    int v = idx[2 * t + 1];
    unsigned long long b = __ballot(v == 0);
    if (t == 0) *flag = (b == 0xFFFFFFFFFFFFFFFFULL) ? 1 : 0;
}

__device__ __forceinline__ int load_idx(const int* __restrict__ idx, long long pos, int is64) {
    return is64 ? idx[2 * pos] : idx[pos];
}

__global__ void count_edges_kernel(const int* __restrict__ idx, const int* __restrict__ flag,
                                   int* __restrict__ counts, int E, int N) {
    int e = blockIdx.x * blockDim.x + threadIdx.x;
    if (e >= E) return;
    int is64 = *flag;
    int d = load_idx(idx, (long long)E + e, is64);
    if ((unsigned)d < (unsigned)N) atomicAdd(&counts[d], 1);
}

// Hierarchical scan: scan1 (local excl scan per 1024-block) -> scan2 (scan partials)
// -> scan3 (add prefix, emit offsets/cursor/dis).
__global__ __launch_bounds__(1024) void scan1_kernel(const int* __restrict__ counts,
                                                     int* __restrict__ offsets,
                                                     int* __restrict__ partials, int n) {
    __shared__ int buf[1024];
    int i = blockIdx.x * 1024 + threadIdx.x;
    int v = (i < n) ? counts[i] : 0;
    buf[threadIdx.x] = v;
    __syncthreads();
    #pragma unroll
    for (int off = 1; off < 1024; off <<= 1) {
        int t = (threadIdx.x >= (unsigned)off) ? buf[threadIdx.x - off] : 0;
        __syncthreads();
        buf[threadIdx.x] += t;
        __syncthreads();
    }
    if (i < n) offsets[i] = buf[threadIdx.x] - v;    // local exclusive
    if (threadIdx.x == 1023) partials[blockIdx.x] = buf[1023];
}

__global__ void scan2_kernel(int* __restrict__ partials, int* __restrict__ offsets,
                             int nb, int n) {
    if (threadIdx.x == 0 && blockIdx.x == 0) {
        int s = 0;
        for (int b = 0; b < nb; ++b) { int t = partials[b]; partials[b] = s; s += t; }
        offsets[n] = s;
    }
}

__global__ __launch_bounds__(1024) void scan3_kernel(const int* __restrict__ counts,
                                                     int* __restrict__ offsets,
                                                     int* __restrict__ cursor,
                                                     float* __restrict__ dis,
                                                     const int* __restrict__ partials, int n) {
    int i = blockIdx.x * 1024 + threadIdx.x;
    if (i >= n) return;
    int o = offsets[i] + partials[blockIdx.x];
    offsets[i] = o;
    cursor[i] = o;
    dis[i] = rsqrtf((float)(counts[i] + 1));
}

__global__ void fill_csr_kernel(const int* __restrict__ idx, const int* __restrict__ flag,
                                int* __restrict__ cursor, int* __restrict__ csr_src,
                                int E, int N) {
    int e = blockIdx.x * blockDim.x + threadIdx.x;
    if (e >= E) return;
    int is64 = *flag;
    int s = load_idx(idx, e, is64);
    int d = load_idx(idx, (long long)E + e, is64);
    if ((unsigned)d < (unsigned)N) {
        int pos = atomicAdd(&cursor[d], 1);
        csr_src[pos] = ((unsigned)s < (unsigned)N) ? s : 0;
    }
}

// Transpose-convert W1 [512][256] -> w1t fp16 [256][512], W2 [256][64] -> w2t fp16 [64][256].
__global__ void wt_kernel(const float* __restrict__ W1, const float* __restrict__ W2,
                          _Float16* __restrict__ w1t, _Float16* __restrict__ w2t) {
    int p = blockIdx.x * 256 + threadIdx.x;
    if (p < 512 * 256) {
        int k = p >> 8, n = p & 255;
        w1t[n * 512 + k] = (_Float16)W1[p];
    } else {
        int q = p - 512 * 256;
        if (q < 256 * 64) {
            int k = q >> 6, n = q & 63;
            w2t[n * 256 + k] = (_Float16)W2[q];
        }
    }
}

// ---------------------------------------------------------------------------
// GEMM1: h1[M,256] = fp16( (x[M,512] @ W1) * dis[row] ), MFMA 16x16x32 f16.
// Tile 128 x 256 (full N), BK=32, 256 threads = 4 waves, wave-tile 64x128.
// LDS layout k-blocked: As[kb][row][8], Bs[kb][n][8]  (conflict-free b128).
// ---------------------------------------------------------------------------
__global__ __launch_bounds__(256, 1) void gemm1_kernel(
        const float* __restrict__ x, const _Float16* __restrict__ w1t,
        const float* __restrict__ dis, _Float16* __restrict__ h1, int M) {
    __shared__ _Float16 As[4 * 128 * 8];
    __shared__ _Float16 Bs[4 * 256 * 8];
    const int tid = threadIdx.x;
    const int brow = blockIdx.x * 128;
    const int w = tid >> 6, lane = tid & 63;
    const int wr = w >> 1, wc = w & 1;
    const int lrow = lane & 15, lkb = lane >> 4;

    f32x4_t acc[4][8];
    #pragma unroll
    for (int mi = 0; mi < 4; ++mi)
        #pragma unroll
        for (int nj = 0; nj < 8; ++nj) acc[mi][nj] = (f32x4_t)0.f;

    for (int k0 = 0; k0 < 512; k0 += 32) {
        // Stage A (f32 -> fp16): 512 pieces of 8 elems; 2 per thread.
        #pragma unroll
        for (int i = 0; i < 2; ++i) {
            int p = tid + i * 256;
            int row = p >> 2, kb = p & 3;
            int gr = brow + row;
            float4 u = make_float4(0.f, 0.f, 0.f, 0.f);
            float4 v = make_float4(0.f, 0.f, 0.f, 0.f);
            if (gr < M) {
                const float* src = &x[(size_t)gr * 512 + k0 + kb * 8];
                u = *(const float4*)src;
                v = *(const float4*)(src + 4);
            }
            half8_t h;
            h[0] = (_Float16)u.x; h[1] = (_Float16)u.y;
            h[2] = (_Float16)u.z; h[3] = (_Float16)u.w;
            h[4] = (_Float16)v.x; h[5] = (_Float16)v.y;
            h[6] = (_Float16)v.z; h[7] = (_Float16)v.w;
            *(half8_t*)&As[((kb << 7) + row) << 3] = h;
        }
        // Stage B (already fp16): 1024 pieces; 4 per thread.
        #pragma unroll
        for (int i = 0; i < 4; ++i) {
            int p = tid + i * 256;
            int n = p >> 2, kb = p & 3;
            half8_t h = *(const half8_t*)&w1t[(size_t)n * 512 + k0 + kb * 8];
            *(half8_t*)&Bs[((kb << 8) + n) << 3] = h;
        }
        __syncthreads();
        half8_t a[4], b[8];
        #pragma unroll
        for (int mi = 0; mi < 4; ++mi)
            a[mi] = *(const half8_t*)&As[((lkb << 7) + wr * 64 + mi * 16 + lrow) << 3];
        #pragma unroll
        for (int nj = 0; nj < 8; ++nj)
            b[nj] = *(const half8_t*)&Bs[((lkb << 8) + wc * 128 + nj * 16 + lrow) << 3];
        #pragma unroll
        for (int mi = 0; mi < 4; ++mi)
            #pragma unroll
            for (int nj = 0; nj < 8; ++nj)
                acc[mi][nj] = __builtin_amdgcn_mfma_f32_16x16x32_f16(a[mi], b[nj], acc[mi][nj], 0, 0, 0);
        __syncthreads();
    }
    // Epilogue: C/D layout col=lane&15, row=(lane>>4)*4+r.
    #pragma unroll
    for (int mi = 0; mi < 4; ++mi) {
        #pragma unroll
        for (int r = 0; r < 4; ++r) {
            int grow = brow + wr * 64 + mi * 16 + (lane >> 4) * 4 + r;
            if (grow >= M) continue;
            float s = dis[grow];
            #pragma unroll
            for (int nj = 0; nj < 8; ++nj) {
                int col = wc * 128 + nj * 16 + lrow;
                h1[(size_t)grow * 256 + col] = (_Float16)(acc[mi][nj][r] * s);
            }
        }
    }
}

// ---------------------------------------------------------------------------
// GEMM2: h2[M,64] = fp16( (a1[M,256] @ W2) * dis[row] ). Tile 64x64, 4 waves,
// wave = 16 rows x 64 cols (1x4 frags). K=256.
// ---------------------------------------------------------------------------
__global__ __launch_bounds__(256) void gemm2_kernel(
        const _Float16* __restrict__ a1, const _Float16* __restrict__ w2t,
        const float* __restrict__ dis, _Float16* __restrict__ h2, int M) {
    __shared__ _Float16 As[4 * 64 * 8];
    __shared__ _Float16 Bs[4 * 64 * 8];
    const int tid = threadIdx.x;
    const int brow = blockIdx.x * 64;
    const int w = tid >> 6, lane = tid & 63;
    const int lrow = lane & 15, lkb = lane >> 4;

    f32x4_t acc[4];
    #pragma unroll
    for (int nj = 0; nj < 4; ++nj) acc[nj] = (f32x4_t)0.f;

    for (int k0 = 0; k0 < 256; k0 += 32) {
        {   // Stage A: 256 pieces, 1 per thread.
            int row = tid >> 2, kb = tid & 3;
            int gr = brow + row;
            half8_t h = (half8_t)(_Float16)0.f;
            if (gr < M) h = *(const half8_t*)&a1[(size_t)gr * 256 + k0 + kb * 8];
            *(half8_t*)&As[((kb << 6) + row) << 3] = h;
            // Stage B: 256 pieces, 1 per thread.
            int n = row;
            half8_t hb = *(const half8_t*)&w2t[(size_t)n * 256 + k0 + kb * 8];
            *(half8_t*)&Bs[((kb << 6) + n) << 3] = hb;
        }
        __syncthreads();
        half8_t a = *(const half8_t*)&As[((lkb << 6) + w * 16 + lrow) << 3];
        half8_t b[4];
        #pragma unroll
        for (int nj = 0; nj < 4; ++nj)
            b[nj] = *(const half8_t*)&Bs[((lkb << 6) + nj * 16 + lrow) << 3];
        #pragma unroll
        for (int nj = 0; nj < 4; ++nj)
            acc[nj] = __builtin_amdgcn_mfma_f32_16x16x32_f16(a, b[nj], acc[nj], 0, 0, 0);
        __syncthreads();
    }
    #pragma unroll
    for (int r = 0; r < 4; ++r) {
        int grow = brow + w * 16 + (lane >> 4) * 4 + r;
        if (grow >= M) continue;
        float s = dis[grow];
        #pragma unroll
        for (int nj = 0; nj < 4; ++nj)
            h2[(size_t)grow * 64 + nj * 16 + lrow] = (_Float16)(acc[nj][r] * s);
    }
}

__device__ __forceinline__ float4 up4(uint2 v) {
    __half2 h0 = *reinterpret_cast<__half2*>(&v.x);
    __half2 h1 = *reinterpret_cast<__half2*>(&v.y);
    float2 a = __half22float2(h0), b = __half22float2(h1);
    return make_float4(a.x, a.y, b.x, b.y);
}

// agg over 256-wide fp16 rows: block per node, 4 waves = edge slots, lane = uint2 (4 fp16).
__global__ __launch_bounds__(256) void agg256_kernel(
        const _Float16* __restrict__ g, const int* __restrict__ offsets,
        const int* __restrict__ csr_src, const float* __restrict__ dis,
        const float* __restrict__ bias, _Float16* __restrict__ out) {
    const int node = blockIdx.x;
    const int w = threadIdx.x >> 6;
    const int lane = threadIdx.x & 63;
    const uint2* gv = (const uint2*)g;            // row = 64 uint2
    float4 acc = make_float4(0.f, 0.f, 0.f, 0.f);
    const int s0 = offsets[node], s1 = offsets[node + 1];
    for (int e = s0 + w; e < s1; e += 4) {
        int s = csr_src[e];
        float4 v = up4(gv[(size_t)s * 64 + lane]);
        acc.x += v.x; acc.y += v.y; acc.z += v.z; acc.w += v.w;
    }
    if (w == 0) {
        float4 v = up4(gv[(size_t)node * 64 + lane]);
        acc.x += v.x; acc.y += v.y; acc.z += v.z; acc.w += v.w;
    }
    __shared__ float4 red[4][64];
    red[w][lane] = acc;
    __syncthreads();
    if (w == 0) {
        float4 a = red[0][lane], b = red[1][lane], c = red[2][lane], d = red[3][lane];
        float s = dis[node];
        float4 bb = ((const float4*)bias)[lane];
        float4 o;
        o.x = fmaxf(fmaf(s, a.x + b.x + c.x + d.x, bb.x), 0.f);
        o.y = fmaxf(fmaf(s, a.y + b.y + c.y + d.y, bb.y), 0.f);
        o.z = fmaxf(fmaf(s, a.z + b.z + c.z + d.z, bb.z), 0.f);
        o.w = fmaxf(fmaf(s, a.w + b.w + c.w + d.w, bb.w), 0.f);
        __half2 p0 = __float22half2_rn(make_float2(o.x, o.y));
        __half2 p1 = __float22half2_rn(make_float2(o.z, o.w));
        uint2 pv;
        pv.x = *reinterpret_cast<unsigned*>(&p0);
        pv.y = *reinterpret_cast<unsigned*>(&p1);
        ((uint2*)out)[(size_t)node * 64 + lane] = pv;
    }
}

// agg over 64-wide fp16 rows -> f32 out. Wave per node; lane = 4 edge-slots x 16 uint2.
__global__ __launch_bounds__(256) void agg64_kernel(
        const _Float16* __restrict__ g, const int* __restrict__ offsets,
        const int* __restrict__ csr_src, const float* __restrict__ dis,
        const float* __restrict__ bias, float* __restrict__ out, int n_nodes) {
    const int node = blockIdx.x * 4 + (threadIdx.x >> 6);
    if (node >= n_nodes) return;
    const int lane = threadIdx.x & 63;
    const int eslot = lane >> 4;
    const int c = lane & 15;
    const uint2* gv = (const uint2*)g;            // row = 16 uint2
    float4 acc = make_float4(0.f, 0.f, 0.f, 0.f);
    const int s0 = offsets[node], s1 = offsets[node + 1];
    for (int e = s0 + eslot; e < s1; e += 4) {
        int s = csr_src[e];
        float4 v = up4(gv[(size_t)s * 16 + c]);
        acc.x += v.x; acc.y += v.y; acc.z += v.z; acc.w += v.w;
    }
    if (eslot == 0) {
        float4 v = up4(gv[(size_t)node * 16 + c]);
        acc.x += v.x; acc.y += v.y; acc.z += v.z; acc.w += v.w;
    }
    #pragma unroll
    for (int m = 16; m <= 32; m <<= 1) {
        acc.x += __shfl_xor(acc.x, m);
        acc.y += __shfl_xor(acc.y, m);
        acc.z += __shfl_xor(acc.z, m);
        acc.w += __shfl_xor(acc.w, m);
    }
    if (eslot == 0) {
        float s = dis[node];
        float4 bb = ((const float4*)bias)[c];
        float4 o;
        o.x = fmaf(s, acc.x, bb.x);
        o.y = fmaf(s, acc.y, bb.y);
        o.z = fmaf(s, acc.z, bb.z);
        o.w = fmaf(s, acc.w, bb.w);
        ((float4*)out)[(size_t)node * 16 + c] = o;
    }
}

extern "C" void kernel_launch(void* const* d_in, const int* in_sizes, int n_in,
                              void* d_out, int out_size, void* d_ws, size_t ws_size,
                              hipStream_t stream) {
    const float* x  = (const float*)d_in[0];
    const float* W1 = (const float*)d_in[1];
    const float* b1 = (const float*)d_in[2];
    const float* W2 = (const float*)d_in[3];
    const float* b2 = (const float*)d_in[4];
    const int* eidx = (const int*)d_in[5];

    const int HID = in_sizes[2];            // 256
    const int OUT = in_sizes[4];            // 64
    const int IN  = in_sizes[1] / HID;      // 512
    const int N   = in_sizes[0] / IN;       // 50000
    const int E   = in_sizes[5] / 2;        // 800000

    char* ws = (char*)d_ws;
    size_t off = 0;
    auto alloc = [&](size_t bytes) {
        off = (off + 255) & ~(size_t)255;
        char* p = ws + off;
        off += bytes;
        return p;
    };
    float* dis     = (float*)alloc((size_t)N * 4);
    int* counts    = (int*)alloc((size_t)N * 4);
    int* offsets   = (int*)alloc((size_t)(N + 1) * 4);
    int* cursor    = (int*)alloc((size_t)N * 4);
    int* partials  = (int*)alloc(4096);
    int* flag      = (int*)alloc(256);
    int* csr_src   = (int*)alloc((size_t)E * 4);
    _Float16* w1t  = (_Float16*)alloc((size_t)IN * HID * 2);
    _Float16* w2t  = (_Float16*)alloc((size_t)HID * OUT * 2);
    _Float16* h1   = (_Float16*)alloc((size_t)N * HID * 2);
    _Float16* a1   = (_Float16*)alloc((size_t)N * HID * 2);
    _Float16* h2   = (_Float16*)alloc((size_t)N * OUT * 2);

    const int nb = (N + 1023) / 1024;

    hipMemsetAsync(counts, 0, (size_t)N * 4, stream);
    detect_i64_kernel<<<1, 64, 0, stream>>>(eidx, flag);
    count_edges_kernel<<<(E + 255) / 256, 256, 0, stream>>>(eidx, flag, counts, E, N);
    scan1_kernel<<<nb, 1024, 0, stream>>>(counts, offsets, partials, N);
    scan2_kernel<<<1, 64, 0, stream>>>(partials, offsets, nb, N);
    scan3_kernel<<<nb, 1024, 0, stream>>>(counts, offsets, cursor, dis, partials, N);
    fill_csr_kernel<<<(E + 255) / 256, 256, 0, stream>>>(eidx, flag, cursor, csr_src, E, N);
    wt_kernel<<<(IN * HID + HID * OUT + 255) / 256, 256, 0, stream>>>(W1, W2, w1t, w2t);

    // Layer 1
    gemm1_kernel<<<(N + 127) / 128, 256, 0, stream>>>(x, w1t, dis, h1, N);
    agg256_kernel<<<N, 256, 0, stream>>>(h1, offsets, csr_src, dis, b1, a1);

    // Layer 2
    gemm2_kernel<<<(N + 63) / 64, 256, 0, stream>>>(a1, w2t, dis, h2, N);
    agg64_kernel<<<(N + 3) / 4, 256, 0, stream>>>(h2, offsets, csr_src, dis, b2,
                                                  (float*)d_out, N);
}